// Round 3
// baseline (295.874 us; speedup 1.0000x reference)
//
#include <hip/hip_runtime.h>

typedef unsigned short ushort_t;
typedef unsigned char uchar_t;
typedef unsigned int uint_t;
typedef __attribute__((ext_vector_type(8))) short bf16x8;
typedef __attribute__((ext_vector_type(4))) float f32x4;

constexpr int L_   = 3;
constexpr int B_   = 8192;
constexpr int H_   = 1024;
constexpr int DOUT_= 80;
constexpr int NACT_= 4096;
constexpr int G3_  = 3 * H_;
constexpr int BUFELT = (256 + 192) * 64;   // one LDS buffer: A(256x64) + W(192x64)

static __device__ __forceinline__ ushort_t f2bf(float f) {
    uint_t u = __float_as_uint(f);
    uint_t r = (u + 0x7FFFu + ((u >> 16) & 1u)) >> 16;
    return (ushort_t)r;
}

static __device__ __forceinline__ void gll16(const void* g, void* l) {
    __builtin_amdgcn_global_load_lds(
        (const __attribute__((address_space(1))) uint32_t*)g,
        (__attribute__((address_space(3))) uint32_t*)l, 16, 0, 0);
}

#define MFMA(A, B, C) __builtin_amdgcn_mfma_f32_16x16x32_bf16((A), (B), (C), 0, 0, 0)
// swizzled LDS reads: logical k-slot s at row r lives at physical slot s ^ (r&7)
#define RDA(buf, m, ks) (*(const bf16x8*)&(buf)[((wr * 128 + (m) * 16 + fl) << 6) + (((((ks) * 4) + fh) ^ (fl & 7)) << 3)])
#define RDB(buf, g, ks) (*(const bf16x8*)&(buf)[16384 + (((g) * 64 + wc * 16 + fl) << 6) + (((((ks) * 4) + fh) ^ (fl & 7)) << 3)])

// ---------------- prep: convert weights fp32 -> bf16 ----------------
__global__ void prep_convert(const float* __restrict__ wih, const float* __restrict__ whh,
                             const float* __restrict__ wout,
                             ushort_t* __restrict__ oih, ushort_t* __restrict__ ohh,
                             ushort_t* __restrict__ oout) {
    int tid = blockIdx.x * blockDim.x + threadIdx.x;
    int nth = gridDim.x * blockDim.x;
    const int NW = L_ * G3_ * H_ / 4;
    for (int i = tid; i < NW; i += nth) {
        float4 a = ((const float4*)wih)[i];
        ushort4 o; o.x = f2bf(a.x); o.y = f2bf(a.y); o.z = f2bf(a.z); o.w = f2bf(a.w);
        ((ushort4*)oih)[i] = o;
        float4 b = ((const float4*)whh)[i];
        ushort4 p; p.x = f2bf(b.x); p.y = f2bf(b.y); p.z = f2bf(b.z); p.w = f2bf(b.w);
        ((ushort4*)ohh)[i] = p;
    }
    const int NO = DOUT_ * H_ / 4;
    for (int i = tid; i < NO; i += nth) {
        float4 a = ((const float4*)wout)[i];
        ushort4 o; o.x = f2bf(a.x); o.y = f2bf(a.y); o.z = f2bf(a.z); o.w = f2bf(a.w);
        ((ushort4*)oout)[i] = o;
    }
}

// ---------------- prep: gather x0 = encoded[idx], h_b16[l] = hidden[l][idx] ----------------
__global__ void prep_gather(const float* __restrict__ encoded, const float* __restrict__ hidden,
                            const int* __restrict__ idx,
                            ushort_t* __restrict__ x0, ushort_t* __restrict__ hb) {
    const int C4 = H_ / 4;
    const int PER = NACT_ * C4;
    int tid = blockIdx.x * blockDim.x + threadIdx.x;
    int nth = gridDim.x * blockDim.x;
    int total = 4 * PER;
    for (int i = tid; i < total; i += nth) {
        int seg = i / PER;
        int rem = i - seg * PER;
        int r = rem / C4, c = rem % C4;
        int gr = idx[r];
        const float* src = (seg == 0) ? (encoded + (size_t)gr * H_)
                                      : (hidden + ((size_t)(seg - 1) * B_ + gr) * H_);
        float4 v = ((const float4*)src)[c];
        ushort4 o; o.x = f2bf(v.x); o.y = f2bf(v.y); o.z = f2bf(v.z); o.w = f2bf(v.w);
        ushort_t* dst = (seg == 0) ? x0 : (hb + (size_t)(seg - 1) * NACT_ * H_);
        ((ushort4*)(dst + (size_t)r * H_))[c] = o;
    }
}

// ---------------- mask + inactive-row copy (replaces full memcpy) ----------------
__global__ void mask_build(const int* __restrict__ idx, uchar_t* __restrict__ mask) {
    int i = blockIdx.x * blockDim.x + threadIdx.x;
    if (i < NACT_) mask[idx[i]] = 1;
}

__global__ void copy_inactive(const float* __restrict__ hidden, const uchar_t* __restrict__ mask,
                              float* __restrict__ outh) {
    const int total = L_ * B_ * (H_ / 4);
    int i = blockIdx.x * blockDim.x + threadIdx.x;
    int nth = gridDim.x * blockDim.x;
    for (; i < total; i += nth) {
        int row = (i >> 8) & (B_ - 1);          // 256 float4 per row
        if (mask[row]) continue;
        ((float4*)outh)[i] = ((const float4*)hidden)[i];
    }
}

// ---------------- gru: one 16-step K-sweep (one input phase) ----------------
template<bool LAST>
static __device__ __forceinline__ void gru_ph16(
    const ushort_t* __restrict__ sA, const ushort_t* __restrict__ sW,
    const ushort_t* __restrict__ nA, const ushort_t* __restrict__ nW,
    const uint_t* aoff, const uint_t* woff,
    ushort_t* ldsbuf, int wave, int wr, int wc, int fl, int fh,
    f32x4 (&accR)[8], f32x4 (&accZ)[8], f32x4 (&accN)[8])
{
#pragma unroll 2
    for (int kki = 0; kki < 16; ++kki) {
        ushort_t* p = ldsbuf + (kki & 1) * BUFELT;
        ushort_t* q = ldsbuf + ((kki + 1) & 1) * BUFELT;
        // issue next step's staging BEFORE the counted wait (T4: never drain in-loop)
        if (kki < 15) {
#pragma unroll
            for (int t = 0; t < 4; ++t) gll16(sA + aoff[t] + (kki + 1) * 64, q + (wave * 32 + t * 8) * 64);
#pragma unroll
            for (int t = 0; t < 3; ++t) gll16(sW + woff[t] + (kki + 1) * 64, q + 16384 + (wave * 24 + t * 8) * 64);
            asm volatile("s_waitcnt vmcnt(7)" ::: "memory");
        } else if (!LAST) {
#pragma unroll
            for (int t = 0; t < 4; ++t) gll16(nA + aoff[t], q + (wave * 32 + t * 8) * 64);
#pragma unroll
            for (int t = 0; t < 3; ++t) gll16(nW + woff[t], q + 16384 + (wave * 24 + t * 8) * 64);
            asm volatile("s_waitcnt vmcnt(7)" ::: "memory");
        } else {
            asm volatile("s_waitcnt vmcnt(0)" ::: "memory");
        }
        __builtin_amdgcn_s_barrier();          // this step's tile visible to all waves
        bf16x8 bfr[3][2];
#pragma unroll
        for (int pp = 0; pp < 4; ++pp) {
            const int m0 = pp * 2, m1 = pp * 2 + 1;
            bf16x8 a00 = RDA(p, m0, 0), a01 = RDA(p, m0, 1);
            bf16x8 a10 = RDA(p, m1, 0), a11 = RDA(p, m1, 1);
            if (pp == 0) {
#pragma unroll
                for (int g = 0; g < 3; ++g) { bfr[g][0] = RDB(p, g, 0); bfr[g][1] = RDB(p, g, 1); }
            }
            __builtin_amdgcn_s_barrier();
            asm volatile("s_waitcnt lgkmcnt(0)" ::: "memory");
            __builtin_amdgcn_sched_barrier(0);
            __builtin_amdgcn_s_setprio(1);
            accR[m0] = MFMA(a00, bfr[0][0], accR[m0]); accR[m0] = MFMA(a01, bfr[0][1], accR[m0]);
            accR[m1] = MFMA(a10, bfr[0][0], accR[m1]); accR[m1] = MFMA(a11, bfr[0][1], accR[m1]);
            accZ[m0] = MFMA(a00, bfr[1][0], accZ[m0]); accZ[m0] = MFMA(a01, bfr[1][1], accZ[m0]);
            accZ[m1] = MFMA(a10, bfr[1][0], accZ[m1]); accZ[m1] = MFMA(a11, bfr[1][1], accZ[m1]);
            accN[m0] = MFMA(a00, bfr[2][0], accN[m0]); accN[m0] = MFMA(a01, bfr[2][1], accN[m0]);
            accN[m1] = MFMA(a10, bfr[2][0], accN[m1]); accN[m1] = MFMA(a11, bfr[2][1], accN[m1]);
            __builtin_amdgcn_s_setprio(0);
            __builtin_amdgcn_s_barrier();
        }
    }
}

// ---------------- fused GRU layer: 256-row tile, 8-wave, dbuf + counted vmcnt ----------------
__global__ __launch_bounds__(512, 2) void gru_layer(
    const ushort_t* __restrict__ xb, const ushort_t* __restrict__ hb,
    const float* __restrict__ hid_full,
    const ushort_t* __restrict__ wih, const ushort_t* __restrict__ whh,
    const float* __restrict__ bih, const float* __restrict__ bhh,
    const int* __restrict__ idx, float* __restrict__ out_hid,
    ushort_t* __restrict__ xnext)
{
    __shared__ ushort_t lds[2 * BUFELT];                // 112 KB
    const int tid = threadIdx.x;
    const int bid = blockIdx.x;
    const int xcd = bid & 7, loc = bid >> 3;            // 32 blocks per XCD (256 % 8 == 0)
    const int bm = (xcd >> 1) * 4 + (loc & 3);          // 4 row-bands x 8 col-tiles per XCD
    const int bn = (xcd & 1) * 8 + (loc >> 2);
    const int row0 = bm * 256, col0 = bn * 64;
    const int wave = tid >> 6, lane = tid & 63;
    const int wr = wave >> 2, wc = wave & 3;            // 2M x 4N wave grid
    const int fl = lane & 15, fh = lane >> 4;
    const int sr = lane >> 3, ss = (lane & 7) ^ sr;     // DMA row-in-8, inverse-swizzled src slot

    uint_t aoff[4], woff[3];
#pragma unroll
    for (int t = 0; t < 4; ++t)
        aoff[t] = (uint_t)(row0 + wave * 32 + t * 8 + sr) * H_ + ss * 8;
#pragma unroll
    for (int t = 0; t < 3; ++t) {
        int r = wave * 24 + t * 8 + sr;                 // flat W row 0..191 = gate*64 + col
        woff[t] = (uint_t)((r >> 6) * H_ + col0 + (r & 63)) * H_ + ss * 8;
    }

    f32x4 accR[8] = {}, accZ[8] = {}, accNx[8] = {}, accNh[8] = {};

    // prologue: stage step 0 (x / wih, k-tile 0) into buf0
#pragma unroll
    for (int t = 0; t < 4; ++t) gll16(xb + aoff[t], lds + (wave * 32 + t * 8) * 64);
#pragma unroll
    for (int t = 0; t < 3; ++t) gll16(wih + woff[t], lds + 16384 + (wave * 24 + t * 8) * 64);

    gru_ph16<false>(xb, wih, hb, whh, aoff, woff, lds, wave, wr, wc, fl, fh, accR, accZ, accNx);
    gru_ph16<true >(hb, whh, nullptr, nullptr, aoff, woff, lds, wave, wr, wc, fl, fh, accR, accZ, accNh);

    // epilogue: gate math + scatter
    const int c = col0 + wc * 16 + fl;
    const float br_r = bih[c] + bhh[c];
    const float br_z = bih[H_ + c] + bhh[H_ + c];
    const float bi_n = bih[2 * H_ + c];
    const float bh_n = bhh[2 * H_ + c];
#pragma unroll
    for (int m = 0; m < 8; ++m) {
#pragma unroll
        for (int j = 0; j < 4; ++j) {
            const int r = row0 + wr * 128 + m * 16 + fh * 4 + j;
            const float vr = 1.f / (1.f + expf(-(accR[m][j] + br_r)));
            const float vz = 1.f / (1.f + expf(-(accZ[m][j] + br_z)));
            const float vn = tanhf(accNx[m][j] + bi_n + vr * (accNh[m][j] + bh_n));
            const int gr = idx[r];
            const float h0 = hid_full[(size_t)gr * H_ + c];
            const float ho = (1.f - vz) * vn + vz * h0;
            out_hid[(size_t)gr * H_ + c] = ho;
            xnext[(size_t)r * H_ + c] = f2bf(ho);
        }
    }
}

// ---------------- head: y = tanh(x @ w_out^T + b_out), scatter ----------------
__global__ __launch_bounds__(256) void head_gemm(
    const ushort_t* __restrict__ xb, const ushort_t* __restrict__ wo,
    const float* __restrict__ bo, const int* __restrict__ idx,
    float* __restrict__ outy)
{
    __shared__ ushort_t Xs[64][72];
    __shared__ ushort_t Ws[80][72];
    const int tid = threadIdx.x;
    const int row0 = blockIdx.x * 64;
    const int lrow = tid >> 2, lseg = tid & 3;
    const int wave = tid >> 6, lane = tid & 63;
    const int fl = lane & 15, fh = lane >> 4;
    f32x4 acc[5] = {};

    for (int kk = 0; kk < H_; kk += 64) {
        __syncthreads();
        const ushort_t* xp = xb + (size_t)(row0 + lrow) * H_ + kk + lseg * 16;
        *(uint4*)&Xs[lrow][lseg * 16]     = *(const uint4*)xp;
        *(uint4*)&Xs[lrow][lseg * 16 + 8] = *(const uint4*)(xp + 8);
        for (int t = tid; t < 320; t += 256) {
            int r = t >> 2, s = t & 3;
            const ushort_t* wp = wo + (size_t)r * H_ + kk + s * 16;
            *(uint4*)&Ws[r][s * 16]     = *(const uint4*)wp;
            *(uint4*)&Ws[r][s * 16 + 8] = *(const uint4*)(wp + 8);
        }
        __syncthreads();
#pragma unroll
        for (int ks = 0; ks < 64; ks += 32) {
            bf16x8 a = *(const bf16x8*)&Xs[wave * 16 + fl][ks + fh * 8];
#pragma unroll
            for (int nf = 0; nf < 5; ++nf) {
                bf16x8 b = *(const bf16x8*)&Ws[nf * 16 + fl][ks + fh * 8];
                acc[nf] = __builtin_amdgcn_mfma_f32_16x16x32_bf16(a, b, acc[nf], 0, 0, 0);
            }
        }
    }
#pragma unroll
    for (int nf = 0; nf < 5; ++nf) {
        const int c = nf * 16 + fl;
        const float bb = bo[c];
#pragma unroll
        for (int j = 0; j < 4; ++j) {
            const int r = row0 + wave * 16 + fh * 4 + j;
            const float y = tanhf(acc[nf][j] + bb);
            outy[(size_t)idx[r] * DOUT_ + c] = y;
        }
    }
}

extern "C" void kernel_launch(void* const* d_in, const int* in_sizes, int n_in,
                              void* d_out, int out_size, void* d_ws, size_t ws_size,
                              hipStream_t stream) {
    const float* encoded = (const float*)d_in[0];
    const float* hidden  = (const float*)d_in[1];
    const int*   idx     = (const int*)d_in[2];
    const float* w_ih    = (const float*)d_in[3];
    const float* w_hh    = (const float*)d_in[4];
    const float* b_ih    = (const float*)d_in[5];
    const float* b_hh    = (const float*)d_in[6];
    const float* w_out   = (const float*)d_in[7];
    const float* b_out   = (const float*)d_in[8];

    float* outy = (float*)d_out;
    float* outh = outy + (size_t)B_ * DOUT_;

    ushort_t* ws    = (ushort_t*)d_ws;
    ushort_t* wihb  = ws;
    ushort_t* whhb  = wihb + (size_t)L_ * G3_ * H_;
    ushort_t* woutb = whhb + (size_t)L_ * G3_ * H_;
    ushort_t* xb0   = woutb + (size_t)DOUT_ * H_;
    ushort_t* xb1   = xb0 + (size_t)NACT_ * H_;
    ushort_t* hb    = xb1 + (size_t)NACT_ * H_;
    uchar_t*  mask  = (uchar_t*)(hb + (size_t)L_ * NACT_ * H_);

    hipMemsetAsync(outy, 0, (size_t)B_ * DOUT_ * sizeof(float), stream);
    hipMemsetAsync(mask, 0, B_, stream);
    mask_build<<<16, 256, 0, stream>>>(idx, mask);
    prep_convert<<<2048, 256, 0, stream>>>(w_ih, w_hh, w_out, wihb, whhb, woutb);
    prep_gather<<<2048, 256, 0, stream>>>(encoded, hidden, idx, xb0, hb);

    ushort_t* xin = xb0;
    ushort_t* xout = xb1;
    for (int i = 0; i < L_; ++i) {
        gru_layer<<<256, 512, 0, stream>>>(
            xin, hb + (size_t)i * NACT_ * H_, hidden + (size_t)i * B_ * H_,
            wihb + (size_t)i * G3_ * H_, whhb + (size_t)i * G3_ * H_,
            b_ih + (size_t)i * G3_, b_hh + (size_t)i * G3_, idx,
            outh + (size_t)i * B_ * H_, xout);
        ushort_t* t = xin; xin = xout; xout = t;
    }
    head_gemm<<<64, 256, 0, stream>>>(xin, woutb, b_out, idx, outy);
    copy_inactive<<<2048, 256, 0, stream>>>(hidden, mask, outh);
}